// Round 1
// baseline (1015.966 us; speedup 1.0000x reference)
//
#include <hip/hip_runtime.h>
#include <hip/hip_bf16.h>

#define TD 2048      // D (model dim)
#define TF 2048      // F (ffn dim)
#define NE 8         // experts
#define NT 4096      // tokens (4*1024)
#define NTOPK 2

typedef __attribute__((ext_vector_type(4))) float f32x4;
typedef __attribute__((ext_vector_type(8))) short bf16x8;
typedef __attribute__((ext_vector_type(4))) short s16x4;

// ---------------- ws layout (bytes) ----------------
// xbf   : ushort [NT][TD]            16 MB
// act   : ushort [2*NT][TF]          32 MB
// wgu_t : ushort [NE][2*TF][TD]     128 MB   (rows 0..TF-1 = gate col n, TF..2TF-1 = up col n)
// wd_t  : ushort [NE][TD][TF]        64 MB
// probs : float  [NT][NE]
// tok   : int    [NE][NT]
// wt    : float  [NE][NT]
// cnt   : int    [NE]
// off   : int    [NE]
#define WS_XBF   ((size_t)0)
#define WS_ACT   ((size_t)16 << 20)
#define WS_WGU   ((size_t)48 << 20)
#define WS_WD    ((size_t)176 << 20)
#define WS_PROBS ((size_t)240 << 20)
#define WS_TOK   (WS_PROBS + (size_t)NT * NE * 4)
#define WS_WT    (WS_TOK + (size_t)NE * NT * 4)
#define WS_CNT   (WS_WT + (size_t)NE * NT * 4)
#define WS_OFF   (WS_CNT + 64)

__device__ __forceinline__ unsigned short f2bf(float f) {
  union { float f; unsigned u; } v; v.f = f;
  unsigned r = v.u + 0x7FFFu + ((v.u >> 16) & 1u);   // RNE
  return (unsigned short)(r >> 16);
}

__device__ __forceinline__ void gload_lds16(const void* g, void* l) {
  __builtin_amdgcn_global_load_lds(
      (const __attribute__((address_space(1))) void*)g,
      (__attribute__((address_space(3))) void*)l, 16, 0, 0);
}

// ---------------- x fp32 -> bf16 ----------------
__global__ void k_cvt_x(const float* __restrict__ x, unsigned short* __restrict__ xbf) {
  int i = blockIdx.x * 256 + threadIdx.x;
  float4 v = ((const float4*)x)[i];
  s16x4 r;
  r[0] = (short)f2bf(v.x); r[1] = (short)f2bf(v.y);
  r[2] = (short)f2bf(v.z); r[3] = (short)f2bf(v.w);
  ((s16x4*)xbf)[i] = r;
}

// ---------------- router: 1 wave per token ----------------
__global__ void k_router(const float* __restrict__ x, const float* __restrict__ rw,
                         const float* __restrict__ rb, float* __restrict__ probs,
                         int* __restrict__ tok, float* __restrict__ wt,
                         int* __restrict__ counts) {
  const int t = blockIdx.x;
  const int l = threadIdx.x;
  const float* xr = x + (size_t)t * TD;
  float a0 = 0, a1 = 0, a2 = 0, a3 = 0, a4 = 0, a5 = 0, a6 = 0, a7 = 0;
#pragma unroll 4
  for (int j = 0; j < TD / 64; j++) {
    int d = j * 64 + l;
    float xv = xr[d];
    const float4* wp = (const float4*)(rw + (size_t)d * NE);
    float4 w0 = wp[0], w1 = wp[1];
    a0 += xv * w0.x; a1 += xv * w0.y; a2 += xv * w0.z; a3 += xv * w0.w;
    a4 += xv * w1.x; a5 += xv * w1.y; a6 += xv * w1.z; a7 += xv * w1.w;
  }
#pragma unroll
  for (int off = 32; off > 0; off >>= 1) {
    a0 += __shfl_xor(a0, off); a1 += __shfl_xor(a1, off);
    a2 += __shfl_xor(a2, off); a3 += __shfl_xor(a3, off);
    a4 += __shfl_xor(a4, off); a5 += __shfl_xor(a5, off);
    a6 += __shfl_xor(a6, off); a7 += __shfl_xor(a7, off);
  }
  if (l == 0) {
    float lg[NE] = { a0 + rb[0], a1 + rb[1], a2 + rb[2], a3 + rb[3],
                     a4 + rb[4], a5 + rb[5], a6 + rb[6], a7 + rb[7] };
    float mx = lg[0];
#pragma unroll
    for (int e = 1; e < NE; e++) mx = fmaxf(mx, lg[e]);
    float pe[NE]; float s = 0.f;
#pragma unroll
    for (int e = 0; e < NE; e++) { pe[e] = __expf(lg[e] - mx); s += pe[e]; }
    float inv = 1.f / s;
#pragma unroll
    for (int e = 0; e < NE; e++) probs[(size_t)t * NE + e] = pe[e] * inv;
    // top-2 (stable: earliest index wins ties, matches lax.top_k)
    int i0 = 0; float b0 = lg[0];
#pragma unroll
    for (int e = 1; e < NE; e++) if (lg[e] > b0) { b0 = lg[e]; i0 = e; }
    int i1 = (i0 == 0) ? 1 : 0; float b1 = lg[i1];
#pragma unroll
    for (int e = 0; e < NE; e++)
      if (e != i0 && lg[e] > b1) { b1 = lg[e]; i1 = e; }
    float e1 = __expf(b1 - b0);
    float rs = 1.f / (1.f + e1);
    float w0v = rs;          // softmax of [b0, b1]
    float w1v = e1 * rs;
    int p0 = atomicAdd(&counts[i0], 1);
    tok[i0 * NT + p0] = t; wt[i0 * NT + p0] = w0v;
    int p1 = atomicAdd(&counts[i1], 1);
    tok[i1 * NT + p1] = t; wt[i1 * NT + p1] = w1v;
  }
}

// ---------------- finalize: mean_probs, offsets, loads, loss ----------------
__global__ void k_finalize(const float* __restrict__ probs, const int* __restrict__ counts,
                           int* __restrict__ offsets, float* __restrict__ tail) {
  __shared__ float sh[4 * NE];
  int tid = threadIdx.x;
  float s[NE] = {0, 0, 0, 0, 0, 0, 0, 0};
  for (int t = tid; t < NT; t += 256) {
#pragma unroll
    for (int e = 0; e < NE; e++) s[e] += probs[(size_t)t * NE + e];
  }
#pragma unroll
  for (int off = 32; off > 0; off >>= 1) {
#pragma unroll
    for (int e = 0; e < NE; e++) s[e] += __shfl_xor(s[e], off);
  }
  if ((tid & 63) == 0) {
#pragma unroll
    for (int e = 0; e < NE; e++) sh[(tid >> 6) * NE + e] = s[e];
  }
  __syncthreads();
  if (tid == 0) {
    float loss = 0.f; int off = 0;
#pragma unroll
    for (int e = 0; e < NE; e++) {
      float mp = (sh[e] + sh[NE + e] + sh[2 * NE + e] + sh[3 * NE + e]) * (1.f / NT);
      int c = counts[e];
      offsets[e] = off; off += c;
      float df = (float)c / (float)(NT * NTOPK);
      tail[e] = df;
      loss += df * mp;
    }
    tail[NE] = 0.01f * (float)NE * loss;
  }
}

// ---------------- transpose + fp32->bf16 weights ----------------
// REMAP=1: gate/up de-interleave (src col g -> out row (g>>1) + (g&1)*TF)
template <int REMAP>
__global__ void k_transpose(const float* __restrict__ W, unsigned short* __restrict__ Wt,
                            int R /*src rows (k)*/, int C /*src cols*/) {
  __shared__ unsigned short tile[64][72];
  const int e = blockIdx.z;
  const float* We = W + (size_t)e * R * C;
  unsigned short* Ot = Wt + (size_t)e * R * C;
  const int k0 = blockIdx.y * 64, c0 = blockIdx.x * 64;
  const int tid = threadIdx.x;
  {
    const int lr = tid >> 2, lq = tid & 3;
    const float* src = We + (size_t)(k0 + lr) * C + c0 + lq * 16;
#pragma unroll
    for (int q = 0; q < 4; q++) {
      float4 v = *(const float4*)(src + q * 4);
      int c = lq * 16 + q * 4;
      tile[lr][c + 0] = f2bf(v.x); tile[lr][c + 1] = f2bf(v.y);
      tile[lr][c + 2] = f2bf(v.z); tile[lr][c + 3] = f2bf(v.w);
    }
  }
  __syncthreads();
  {
    const int oc = tid >> 2, kq = tid & 3;
    const int n_src = c0 + oc;
    const int orow = REMAP ? ((n_src >> 1) + (n_src & 1) * TF) : n_src;
    unsigned short* dst = Ot + (size_t)orow * R + k0 + kq * 16;
#pragma unroll
    for (int g = 0; g < 4; g++) {
      s16x4 v;
#pragma unroll
      for (int i = 0; i < 4; i++) v[i] = (short)tile[kq * 16 + g * 4 + i][oc];
      *(s16x4*)(dst + g * 4) = v;
    }
  }
}

// ---------------- GEMM1: act = activation(xbf[tok] @ Wgu + b) ----------------
// tile: 128 rows x 64 act-cols (=128 gu-cols: gate rows n0.., up rows TF+n0..)
__global__ __launch_bounds__(256) void k_gemm1(
    const unsigned short* __restrict__ xbf, const int* __restrict__ tok,
    const int* __restrict__ counts, const int* __restrict__ offsets,
    const unsigned short* __restrict__ wgu, const float* __restrict__ bgu,
    unsigned short* __restrict__ act) {
  const int e = blockIdx.z;
  const int cnt = counts[e];
  const int m0 = blockIdx.y * 128;
  if (m0 >= cnt) return;
  const int n0 = blockIdx.x * 64;
  const int offe = offsets[e];
  const unsigned short* Bg = wgu + (size_t)e * (2 * TF) * TD;
  __shared__ unsigned short lA[128 * 32];
  __shared__ unsigned short lB[128 * 32];
  const int tid = threadIdx.x, wid = tid >> 6, lane = tid & 63;

  const unsigned short* srcA[2];
  const unsigned short* srcB[2];
#pragma unroll
  for (int j = 0; j < 2; j++) {
    int idx = j * 256 + tid, r = idx >> 2, q = idx & 3;
    int rr = min(m0 + r, cnt - 1);
    srcA[j] = xbf + (size_t)tok[e * NT + rr] * TD + q * 8;
    int srow = (r < 64) ? (n0 + r) : (TF + n0 + (r - 64));
    srcB[j] = Bg + (size_t)srow * TD + q * 8;
  }
  const int kc = (lane >> 4) * 8, cA = lane & 15;
  int aoff[2], boff[8];
#pragma unroll
  for (int mr = 0; mr < 2; mr++) aoff[mr] = (wid * 32 + mr * 16 + cA) * 32 + kc;
#pragma unroll
  for (int nf = 0; nf < 8; nf++) boff[nf] = (nf * 16 + cA) * 32 + kc;

  f32x4 acc[2][8] = {};

  for (int kt = 0; kt < TD / 32; kt++) {
    const int k0 = kt * 32;
    __syncthreads();
    gload_lds16(srcA[0] + k0, &lA[(size_t)tid * 8]);
    gload_lds16(srcA[1] + k0, &lA[(size_t)(256 + tid) * 8]);
    gload_lds16(srcB[0] + k0, &lB[(size_t)tid * 8]);
    gload_lds16(srcB[1] + k0, &lB[(size_t)(256 + tid) * 8]);
    __syncthreads();
    bf16x8 af0 = *(const bf16x8*)&lA[aoff[0]];
    bf16x8 af1 = *(const bf16x8*)&lA[aoff[1]];
#pragma unroll
    for (int nf = 0; nf < 8; nf++) {
      bf16x8 bfr = *(const bf16x8*)&lB[boff[nf]];
      acc[0][nf] = __builtin_amdgcn_mfma_f32_16x16x32_bf16(af0, bfr, acc[0][nf], 0, 0, 0);
      acc[1][nf] = __builtin_amdgcn_mfma_f32_16x16x32_bf16(af1, bfr, acc[1][nf], 0, 0, 0);
    }
  }

  const float* be = bgu + (size_t)e * 2 * TF;
#pragma unroll
  for (int nf = 0; nf < 4; nf++) {
    int col = n0 + nf * 16 + cA;
    float bgate = be[2 * col], bup = be[2 * col + 1];
#pragma unroll
    for (int mr = 0; mr < 2; mr++) {
#pragma unroll
      for (int r = 0; r < 4; r++) {
        int row = wid * 32 + mr * 16 + (lane >> 4) * 4 + r;
        if (m0 + row < cnt) {
          float g = acc[mr][nf][r] + bgate;
          float u = acc[mr][nf + 4][r] + bup;
          g = fminf(g, 7.0f);
          u = fminf(fmaxf(u, -7.0f), 7.0f);
          float glu = g * (1.0f / (1.0f + __expf(-1.702f * g)));
          float a = (u + 1.0f) * glu;
          act[(size_t)(offe + m0 + row) * TF + col] = f2bf(a);
        }
      }
    }
  }
}

// ---------------- GEMM2: out[tok] += w * (act @ Wd + b_down) ----------------
__global__ __launch_bounds__(256) void k_gemm2(
    const unsigned short* __restrict__ act, const int* __restrict__ tok,
    const float* __restrict__ wt, const int* __restrict__ counts,
    const int* __restrict__ offsets, const unsigned short* __restrict__ wd,
    const float* __restrict__ bd, float* __restrict__ out) {
  const int e = blockIdx.z;
  const int cnt = counts[e];
  const int m0 = blockIdx.y * 128;
  if (m0 >= cnt) return;
  const int d0 = blockIdx.x * 128;
  const int offe = offsets[e];
  const unsigned short* Bd = wd + (size_t)e * TD * TF;
  __shared__ unsigned short lA[128 * 32];
  __shared__ unsigned short lB[128 * 32];
  const int tid = threadIdx.x, wid = tid >> 6, lane = tid & 63;

  const unsigned short* srcA[2];
  const unsigned short* srcB[2];
#pragma unroll
  for (int j = 0; j < 2; j++) {
    int idx = j * 256 + tid, r = idx >> 2, q = idx & 3;
    int rr = min(m0 + r, cnt - 1);
    srcA[j] = act + (size_t)(offe + rr) * TF + q * 8;
    srcB[j] = Bd + (size_t)(d0 + r) * TF + q * 8;
  }
  const int kc = (lane >> 4) * 8, cA = lane & 15;
  int aoff[2], boff[8];
#pragma unroll
  for (int mr = 0; mr < 2; mr++) aoff[mr] = (wid * 32 + mr * 16 + cA) * 32 + kc;
#pragma unroll
  for (int nf = 0; nf < 8; nf++) boff[nf] = (nf * 16 + cA) * 32 + kc;

  f32x4 acc[2][8] = {};

  for (int kt = 0; kt < TF / 32; kt++) {
    const int k0 = kt * 32;
    __syncthreads();
    gload_lds16(srcA[0] + k0, &lA[(size_t)tid * 8]);
    gload_lds16(srcA[1] + k0, &lA[(size_t)(256 + tid) * 8]);
    gload_lds16(srcB[0] + k0, &lB[(size_t)tid * 8]);
    gload_lds16(srcB[1] + k0, &lB[(size_t)(256 + tid) * 8]);
    __syncthreads();
    bf16x8 af0 = *(const bf16x8*)&lA[aoff[0]];
    bf16x8 af1 = *(const bf16x8*)&lA[aoff[1]];
#pragma unroll
    for (int nf = 0; nf < 8; nf++) {
      bf16x8 bfr = *(const bf16x8*)&lB[boff[nf]];
      acc[0][nf] = __builtin_amdgcn_mfma_f32_16x16x32_bf16(af0, bfr, acc[0][nf], 0, 0, 0);
      acc[1][nf] = __builtin_amdgcn_mfma_f32_16x16x32_bf16(af1, bfr, acc[1][nf], 0, 0, 0);
    }
  }

  const float* bde = bd + (size_t)e * TD;
#pragma unroll
  for (int nf = 0; nf < 8; nf++) {
    int col = d0 + nf * 16 + cA;
    float bc = bde[col];
#pragma unroll
    for (int mr = 0; mr < 2; mr++) {
#pragma unroll
      for (int r = 0; r < 4; r++) {
        int row = wid * 32 + mr * 16 + (lane >> 4) * 4 + r;
        int rowe = m0 + row;
        if (rowe < cnt) {
          float v = acc[mr][nf][r] + bc;
          int tk = tok[e * NT + rowe];
          float w = wt[e * NT + rowe];
          atomicAdd(&out[(size_t)tk * TD + col], w * v);
        }
      }
    }
  }
}

extern "C" void kernel_launch(void* const* d_in, const int* in_sizes, int n_in,
                              void* d_out, int out_size, void* d_ws, size_t ws_size,
                              hipStream_t stream) {
  const float* x   = (const float*)d_in[0];
  const float* rw  = (const float*)d_in[1];
  const float* rb  = (const float*)d_in[2];
  const float* wgu = (const float*)d_in[3];
  const float* bgu = (const float*)d_in[4];
  const float* wdn = (const float*)d_in[5];
  const float* bdn = (const float*)d_in[6];
  float* out = (float*)d_out;
  char* ws = (char*)d_ws;

  unsigned short* xbf  = (unsigned short*)(ws + WS_XBF);
  unsigned short* act  = (unsigned short*)(ws + WS_ACT);
  unsigned short* wgut = (unsigned short*)(ws + WS_WGU);
  unsigned short* wdt  = (unsigned short*)(ws + WS_WD);
  float* probs = (float*)(ws + WS_PROBS);
  int*   tokl  = (int*)(ws + WS_TOK);
  float* wtl   = (float*)(ws + WS_WT);
  int*   cnts  = (int*)(ws + WS_CNT);
  int*   offs  = (int*)(ws + WS_OFF);

  hipMemsetAsync(out, 0, (size_t)NT * TD * sizeof(float), stream);
  hipMemsetAsync(cnts, 0, NE * sizeof(int), stream);

  k_cvt_x<<<(NT * TD) / 1024, 256, 0, stream>>>(x, xbf);
  k_router<<<NT, 64, 0, stream>>>(x, rw, rb, probs, tokl, wtl, cnts);
  k_finalize<<<1, 256, 0, stream>>>(probs, cnts, offs, out + (size_t)NT * TD);
  k_transpose<1><<<dim3(4096 / 64, 2048 / 64, NE), 256, 0, stream>>>(wgu, wgut, TD, 2 * TF);
  k_transpose<0><<<dim3(2048 / 64, 2048 / 64, NE), 256, 0, stream>>>(wdn, wdt, TF, TD);
  k_gemm1<<<dim3(TF / 64, NT / 128, NE), 256, 0, stream>>>(xbf, tokl, cnts, offs, wgut, bgu, act);
  k_gemm2<<<dim3(TD / 128, NT / 128, NE), 256, 0, stream>>>(act, tokl, wtl, cnts, offs, wdt, bdn, out);
}